// Round 9
// baseline (111.356 us; speedup 1.0000x reference)
//
#include <hip/hip_runtime.h>
#include <hip/hip_bf16.h>
#include <stdint.h>

static constexpr int NBATCH = 8;
static constexpr int Cin  = 64;
static constexpr int Cout = 64;
static constexpr int H = 96, W = 96;
static constexpr int HW   = H * W;          // 9216
static constexpr int NPIX = NBATCH * HW;    // 73728
static constexpr int NBLK = NPIX / 64;      // 1152
static constexpr int BLK_PER_BATCH = HW / 64; // 144
static constexpr float EPS = 1e-5f;

typedef short  bf16x8 __attribute__((ext_vector_type(8)));
typedef float  f32x4  __attribute__((ext_vector_type(4)));

__device__ inline uint16_t f2bf(float f) {
    __hip_bfloat16 h = __float2bfloat16(f);
    return *reinterpret_cast<uint16_t*>(&h);
}
__device__ inline float bf2f(uint16_t u) {
    union { uint32_t i; float f; } z;
    z.i = ((uint32_t)u) << 16;
    return z.f;
}

// ---------------------------------------------------------------------------
// Kernel 0: pack weights into MFMA B-fragment order, bf16.
//   layout [sg:72][n][e:8], value = w[n][c][tap], k = sg*8+e, tap=k>>6, c=k&63
// ---------------------------------------------------------------------------
__global__ void repack(const float* __restrict__ w_off,
                       const float* __restrict__ w_def,
                       uint16_t* __restrict__ woffPack,
                       uint16_t* __restrict__ wdefPack) {
    int t0 = blockIdx.x * blockDim.x + threadIdx.x;
    int stride = gridDim.x * blockDim.x;
    for (int i = t0; i < 72 * 32 * 8; i += stride) {
        int e = i & 7;
        int n = (i >> 3) & 31;
        int sg = i >> 8;
        int k = sg * 8 + e;
        int tap = k >> 6, c = k & 63;
        woffPack[i] = (n < 18) ? f2bf(w_off[(n * Cin + c) * 9 + tap]) : (uint16_t)0;
    }
    for (int i = t0; i < 72 * 64 * 8; i += stride) {
        int e = i & 7;
        int n = (i >> 3) & 63;
        int sg = i >> 9;
        int k = sg * 8 + e;
        int tap = k >> 6, c = k & 63;
        wdefPack[i] = f2bf(w_def[(n * Cin + c) * 9 + tap]);
    }
}

// ---------------------------------------------------------------------------
// Kernel 1: transpose x (NCHW f32) -> xT (N,HW,C) bf16. 2 threads/pixel.
// ---------------------------------------------------------------------------
__global__ __launch_bounds__(256) void transpose_x(const float* __restrict__ x,
                                                   uint16_t* __restrict__ xT) {
    int t = blockIdx.x * 256 + threadIdx.x;      // exact grid: NPIX*2 threads
    int pix  = t >> 1;
    int half = t & 1;
    int b = pix / HW, rem = pix % HW;
    const float* xb = x + (size_t)(b * Cin) * HW + rem + (size_t)(half * 32) * HW;
    uint16_t* o = xT + (size_t)pix * 64 + half * 32;
#pragma unroll
    for (int cg = 0; cg < 4; ++cg) {
        bf16x8 v;
#pragma unroll
        for (int e = 0; e < 8; ++e) v[e] = (short)f2bf(xb[(cg * 8 + e) * HW]);
        *reinterpret_cast<bf16x8*>(o + cg * 8) = v;
    }
}

// ---------------------------------------------------------------------------
// Kernel 2: fused deformable block, 512 threads / 64-pixel tile. LDS = 46 KB
// (3 blocks/CU). As (40 KB) holds only 5 taps of DEFORMED im2col at a time:
//   [tapLocal:5][pix:64][slot:8][16B], slot = chunk ^ (pix&7).
//  P2 : offset GEMM, A-fragments straight from global xT (clamp+zero),
//       wave=(wj:2, kq:4) -> osum (alias As) -> offs[64][18]
//  P3a: sample taps 0-3 -> As        P4a: GEMM sg 0-31 (acc in regs)
//  P3b: sample taps 4-8 -> As        P4b: GEMM sg 32-71
//  -> red (alias As) -> y + BN partials
// ---------------------------------------------------------------------------
__global__ __launch_bounds__(512, 6) void fused_deform(
        const uint16_t* __restrict__ xT,
        const uint16_t* __restrict__ woffPack,
        const uint16_t* __restrict__ wdefPack,
        const float* __restrict__ b_off,
        float* __restrict__ y,
        float* __restrict__ partial) {
    __shared__ __attribute__((aligned(16))) char smem[40960];
    __shared__ float offs[64 * 18];       //  4608 B
    __shared__ float s_red[128];          //   512 B
    short* As   = (short*)smem;           // deformed im2col, 5-tap window
    float* osum = (float*)smem;           // [4][64][34] alias (P2 only)
    float* red  = (float*)smem;           // [2][64][66] alias (post-P4b)

    int tid  = threadIdx.x;
    int lane = tid & 63;
    int wv   = tid >> 6;                  // 0..7
    int l15  = lane & 15;
    int lg   = lane >> 4;

    // XCD-aware swizzle: batch b -> XCD b
    int wgid  = (blockIdx.x & 7) * BLK_PER_BATCH + (blockIdx.x >> 3);
    int gpix0 = wgid * 64;
    int b     = gpix0 / HW;
    int rem0  = gpix0 % HW;
    const uint16_t* xTb = xT + (size_t)b * HW * 64;

    // pixel-major mapping for the sampling phases
    int pr   = (wv << 3) + (lane >> 3);   // local pixel 0..63
    int e8   = lane & 7;                  // channel chunk (8 ch = 16B)
    int slot = e8 ^ (pr & 7);             // LDS swizzle (involution)
    int remP = rem0 + pr;
    int hP   = remP / W, wP = remP % W;

    if (tid < 128) s_red[tid] = 0.f;

    // ---- Phase 2: offset GEMM, A from global. wave = (wj=wv&1, kq=wv>>1) ----
    {
        int wj = wv & 1;
        int kq = wv >> 1;
        int sbeg = (kq < 2) ? kq * 5 : 2 + kq * 4;     // 0,5,10,14
        int send = (kq < 2) ? sbeg + 5 : sbeg + 4;
        // per-m pixel coords (named scalars, compile-time m)
        int rm0 = rem0 + l15,      h0_ = rm0 / W, w0_ = rm0 % W;
        int rm1 = rem0 + 16 + l15, h1_ = rm1 / W, w1_ = rm1 % W;
        int rm2 = rem0 + 32 + l15, h2_ = rm2 / W, w2_ = rm2 % W;
        int rm3 = rem0 + 48 + l15, h3_ = rm3 / W, w3_ = rm3 % W;
        f32x4 oacc[4];
#pragma unroll
        for (int m = 0; m < 4; ++m) oacc[m] = (f32x4){0.f, 0.f, 0.f, 0.f};
        for (int s = sbeg; s < send; ++s) {
            int sg  = s * 4 + lg;
            int tap = s >> 1;                       // uniform across lanes
            int ty  = tap / 3 - 1, tx = tap % 3 - 1;
            int ch  = (s & 1) * 4 + lg;
            bf16x8 bb = *reinterpret_cast<const bf16x8*>(
                woffPack + (sg * 32 + wj * 16 + l15) * 8);
#pragma unroll
            for (int m = 0; m < 4; ++m) {
                int hh = (m == 0 ? h0_ : m == 1 ? h1_ : m == 2 ? h2_ : h3_) + ty;
                int ww = (m == 0 ? w0_ : m == 1 ? w1_ : m == 2 ? w2_ : w3_) + tx;
                bool ok = (hh >= 0) && (hh < H) && (ww >= 0) && (ww < W);
                int cy = min(max(hh, 0), H - 1);
                int cx = min(max(ww, 0), W - 1);
                bf16x8 a = *reinterpret_cast<const bf16x8*>(
                    xTb + (cy * W + cx) * 64 + ch * 8);
                if (!ok) a = (bf16x8){0, 0, 0, 0, 0, 0, 0, 0};
                oacc[m] = __builtin_amdgcn_mfma_f32_16x16x32_bf16(a, bb, oacc[m], 0, 0, 0);
            }
        }
#pragma unroll
        for (int m = 0; m < 4; ++m)
#pragma unroll
            for (int r = 0; r < 4; ++r)
                osum[(kq * 64 + m * 16 + lg * 4 + r) * 34 + wj * 16 + l15] = oacc[m][r];
        __syncthreads();
        for (int i = tid; i < 64 * 18; i += 512) {
            int rr = i / 18, o = i - rr * 18;
            offs[i] = osum[rr * 34 + o] + osum[(64 + rr) * 34 + o]
                    + osum[(128 + rr) * 34 + o] + osum[(192 + rr) * 34 + o] + b_off[o];
        }
        __syncthreads();   // osum reads done -> As writable
    }

    // ---- bilinear setup (dedup: lane e8 owns tap e8; tap 8 local) ----
    float hm1 = (float)(hP - 1), wm1 = (float)(wP - 1);
    float w00a, w01a, w10a, w11a; int i00a, i01a, i10a, i11a;
    {
        int t = e8;
        int ty = (t * 11) >> 5;          // t/3 for t in [0,8]
        int tx = t - 3 * ty;
        float dy = offs[pr * 18 + 2 * t];
        float dx = offs[pr * 18 + 2 * t + 1];
        float py = dy + (float)ty + hm1;
        float px = dx + (float)tx + wm1;
        float y0f = floorf(py), x0f = floorf(px);
        float wy1 = py - y0f, wx1 = px - x0f;
        float wy0 = 1.f - wy1, wx0 = 1.f - wx1;
        int iy0 = (int)y0f, ix0 = (int)x0f;
        int iy1 = iy0 + 1,  ix1 = ix0 + 1;
        bool vy0 = (iy0 >= 0) && (iy0 < H), vy1 = (iy1 >= 0) && (iy1 < H);
        bool vx0 = (ix0 >= 0) && (ix0 < W), vx1 = (ix1 >= 0) && (ix1 < W);
        w00a = (vy0 && vx0) ? wy0 * wx0 : 0.f;
        w01a = (vy0 && vx1) ? wy0 * wx1 : 0.f;
        w10a = (vy1 && vx0) ? wy1 * wx0 : 0.f;
        w11a = (vy1 && vx1) ? wy1 * wx1 : 0.f;
        int cy0 = min(max(iy0, 0), H - 1), cy1 = min(max(iy1, 0), H - 1);
        int cx0 = min(max(ix0, 0), W - 1), cx1 = min(max(ix1, 0), W - 1);
        i00a = cy0 * W + cx0; i01a = cy0 * W + cx1;
        i10a = cy1 * W + cx0; i11a = cy1 * W + cx1;
    }
    float w00b, w01b, w10b, w11b; int i00b, i01b, i10b, i11b;
    {
        float dy = offs[pr * 18 + 16];
        float dx = offs[pr * 18 + 17];
        float py = dy + 2.f + hm1;
        float px = dx + 2.f + wm1;
        float y0f = floorf(py), x0f = floorf(px);
        float wy1 = py - y0f, wx1 = px - x0f;
        float wy0 = 1.f - wy1, wx0 = 1.f - wx1;
        int iy0 = (int)y0f, ix0 = (int)x0f;
        int iy1 = iy0 + 1,  ix1 = ix0 + 1;
        bool vy0 = (iy0 >= 0) && (iy0 < H), vy1 = (iy1 >= 0) && (iy1 < H);
        bool vx0 = (ix0 >= 0) && (ix0 < W), vx1 = (ix1 >= 0) && (ix1 < W);
        w00b = (vy0 && vx0) ? wy0 * wx0 : 0.f;
        w01b = (vy0 && vx1) ? wy0 * wx1 : 0.f;
        w10b = (vy1 && vx0) ? wy1 * wx0 : 0.f;
        w11b = (vy1 && vx1) ? wy1 * wx1 : 0.f;
        int cy0 = min(max(iy0, 0), H - 1), cy1 = min(max(iy1, 0), H - 1);
        int cx0 = min(max(ix0, 0), W - 1), cx1 = min(max(ix1, 0), W - 1);
        i00b = cy0 * W + cx0; i01b = cy0 * W + cx1;
        i10b = cy1 * W + cx0; i11b = cy1 * W + cx1;
    }
    const uint16_t* basep = xTb + e8 * 8;
    int lanebase = lane & 56;
    int nf = wv & 3;
    int kh = wv >> 2;
    f32x4 acc[4];
#pragma unroll
    for (int m = 0; m < 4; ++m) acc[m] = (f32x4){0.f, 0.f, 0.f, 0.f};

    // ================= half A: taps 0-3 sample, sg 0-31 GEMM =================
#pragma unroll
    for (int tap = 0; tap < 4; ++tap) {
        int src = lanebase + tap;
        float w00 = __shfl(w00a, src), w01 = __shfl(w01a, src);
        float w10 = __shfl(w10a, src), w11 = __shfl(w11a, src);
        int i00 = __shfl(i00a, src), i01 = __shfl(i01a, src);
        int i10 = __shfl(i10a, src), i11 = __shfl(i11a, src);
        bf16x8 v00 = *reinterpret_cast<const bf16x8*>(basep + i00 * 64);
        bf16x8 v01 = *reinterpret_cast<const bf16x8*>(basep + i01 * 64);
        bf16x8 v10 = *reinterpret_cast<const bf16x8*>(basep + i10 * 64);
        bf16x8 v11 = *reinterpret_cast<const bf16x8*>(basep + i11 * 64);
        bf16x8 outv;
#pragma unroll
        for (int e = 0; e < 8; ++e) {
            float s = w00 * bf2f((uint16_t)v00[e]) + w01 * bf2f((uint16_t)v01[e])
                    + w10 * bf2f((uint16_t)v10[e]) + w11 * bf2f((uint16_t)v11[e]);
            outv[e] = (short)f2bf(s);
        }
        *reinterpret_cast<bf16x8*>(&As[((tap * 64 + pr) * 8 + slot) * 8]) = outv;
    }
    __syncthreads();
#pragma unroll
    for (int i = 0; i < 4; ++i) {
        int sg = kh * 16 + i * 4 + lg;
        bf16x8 bb = *reinterpret_cast<const bf16x8*>(
            wdefPack + (sg * 64 + nf * 16 + l15) * 8);
#pragma unroll
        for (int m = 0; m < 4; ++m) {
            bf16x8 a = *reinterpret_cast<const bf16x8*>(
                &As[(((sg >> 3) * 64 + m * 16 + l15) * 8 + ((sg & 7) ^ (l15 & 7))) * 8]);
            acc[m] = __builtin_amdgcn_mfma_f32_16x16x32_bf16(a, bb, acc[m], 0, 0, 0);
        }
    }
    __syncthreads();   // sg 0-31 reads done -> As writable

    // ================= half B: taps 4-8 sample, sg 32-71 GEMM ================
#pragma unroll
    for (int tap = 4; tap < 9; ++tap) {
        float w00, w01, w10, w11; int i00, i01, i10, i11;
        if (tap < 8) {
            int src = lanebase + tap;
            w00 = __shfl(w00a, src); w01 = __shfl(w01a, src);
            w10 = __shfl(w10a, src); w11 = __shfl(w11a, src);
            i00 = __shfl(i00a, src); i01 = __shfl(i01a, src);
            i10 = __shfl(i10a, src); i11 = __shfl(i11a, src);
        } else {
            w00 = w00b; w01 = w01b; w10 = w10b; w11 = w11b;
            i00 = i00b; i01 = i01b; i10 = i10b; i11 = i11b;
        }
        bf16x8 v00 = *reinterpret_cast<const bf16x8*>(basep + i00 * 64);
        bf16x8 v01 = *reinterpret_cast<const bf16x8*>(basep + i01 * 64);
        bf16x8 v10 = *reinterpret_cast<const bf16x8*>(basep + i10 * 64);
        bf16x8 v11 = *reinterpret_cast<const bf16x8*>(basep + i11 * 64);
        bf16x8 outv;
#pragma unroll
        for (int e = 0; e < 8; ++e) {
            float s = w00 * bf2f((uint16_t)v00[e]) + w01 * bf2f((uint16_t)v01[e])
                    + w10 * bf2f((uint16_t)v10[e]) + w11 * bf2f((uint16_t)v11[e]);
            outv[e] = (short)f2bf(s);
        }
        *reinterpret_cast<bf16x8*>(&As[(((tap - 4) * 64 + pr) * 8 + slot) * 8]) = outv;
    }
    __syncthreads();
#pragma unroll
    for (int i = 0; i < 5; ++i) {
        int sgl = kh * 20 + i * 4 + lg;               // 0..39 local
        bf16x8 bb = *reinterpret_cast<const bf16x8*>(
            wdefPack + ((32 + sgl) * 64 + nf * 16 + l15) * 8);
#pragma unroll
        for (int m = 0; m < 4; ++m) {
            bf16x8 a = *reinterpret_cast<const bf16x8*>(
                &As[(((sgl >> 3) * 64 + m * 16 + l15) * 8 + ((sgl & 7) ^ (l15 & 7))) * 8]);
            acc[m] = __builtin_amdgcn_mfma_f32_16x16x32_bf16(a, bb, acc[m], 0, 0, 0);
        }
    }
    __syncthreads();   // sg 32-71 reads done -> red (alias) writable

    // ---- reduce kh-partials through LDS, write y + BN partials ----
#pragma unroll
    for (int m = 0; m < 4; ++m)
#pragma unroll
        for (int r = 0; r < 4; ++r)
            red[(kh * 64 + m * 16 + lg * 4 + r) * 66 + nf * 16 + l15] = acc[m][r];
    __syncthreads();
    {
        int c  = lane;
        int rg = wv;
        f32x4 v0, v1;
        float s = 0.f, q = 0.f;
#pragma unroll
        for (int k2 = 0; k2 < 8; ++k2) {
            int r = rg * 8 + k2;
            float v = red[r * 66 + c] + red[(64 + r) * 66 + c];
            if (k2 < 4) v0[k2] = v; else v1[k2 - 4] = v;
            s += v; q += v * v;
        }
        float* yp = y + ((size_t)b * Cout + c) * HW + rem0 + rg * 8;
        *reinterpret_cast<f32x4*>(yp)     = v0;
        *reinterpret_cast<f32x4*>(yp + 4) = v1;
        atomicAdd(&s_red[c], s);
        atomicAdd(&s_red[64 + c], q);
    }
    __syncthreads();
    if (tid < 128) partial[(size_t)wgid * 128 + tid] = s_red[tid];
}

// ---------------------------------------------------------------------------
// Kernel 3: single-block BN stats: reduce partial[1152][128] -> scale/shift
// ---------------------------------------------------------------------------
__global__ __launch_bounds__(1024) void bn_stats(const float* __restrict__ partial,
                                                 const float* __restrict__ gamma,
                                                 const float* __restrict__ beta,
                                                 float* __restrict__ stats) {
    __shared__ float red[1024];
    int t = threadIdx.x, ch = t & 127, part = t >> 7;
    float s = 0.f;
    for (int i = part; i < NBLK; i += 8) s += partial[(size_t)i * 128 + ch];
    red[t] = s;
    __syncthreads();
    if (t < 128) {
        float a = 0.f;
#pragma unroll
        for (int p = 0; p < 8; ++p) a += red[p * 128 + ch];
        red[t] = a;
    }
    __syncthreads();
    if (t < 64) {
        float sum = red[t];
        float sq  = red[64 + t];
        float mean = sum / (float)NPIX;
        float var  = sq / (float)NPIX - mean * mean;
        float v    = var + EPS;
        float inv  = rsqrtf(v);
        inv = inv * (1.5f - 0.5f * v * inv * inv);
        float sc = gamma[t] * inv;
        stats[t]      = sc;
        stats[64 + t] = beta[t] - mean * sc;
    }
}

// ---------------------------------------------------------------------------
// Kernel 4: in-place scale/shift/ReLU, float4
// ---------------------------------------------------------------------------
__global__ __launch_bounds__(256) void bn_apply(float* __restrict__ y,
                                                const float* __restrict__ stats) {
    int t = blockIdx.x * blockDim.x + threadIdx.x;
    int e = t * 4;
    int ch = (e / HW) % Cout;
    float sc = stats[ch];
    float sh = stats[64 + ch];
    float4 v = *reinterpret_cast<float4*>(y + e);
    v.x = fmaxf(v.x * sc + sh, 0.f);
    v.y = fmaxf(v.y * sc + sh, 0.f);
    v.z = fmaxf(v.z * sc + sh, 0.f);
    v.w = fmaxf(v.w * sc + sh, 0.f);
    *reinterpret_cast<float4*>(y + e) = v;
}

// ---------------------------------------------------------------------------
extern "C" void kernel_launch(void* const* d_in, const int* in_sizes, int n_in,
                              void* d_out, int out_size, void* d_ws, size_t ws_size,
                              hipStream_t stream) {
    const float* x     = (const float*)d_in[0];
    const float* w_off = (const float*)d_in[1];
    const float* b_off = (const float*)d_in[2];
    const float* w_def = (const float*)d_in[3];
    // d_in[4] = b_def: constant shift, cancels exactly in BatchNorm — omitted
    const float* gamma = (const float*)d_in[5];
    const float* beta  = (const float*)d_in[6];
    float* out = (float*)d_out;
    char*  ws  = (char*)d_ws;

    // ws layout (bytes)
    uint16_t* xT       = (uint16_t*)ws;                    // 9,437,184
    uint16_t* woffPack = (uint16_t*)(ws + 9437184);        //    36,864
    uint16_t* wdefPack = (uint16_t*)(ws + 9474048);        //    73,728
    float*    partial  = (float*)(ws + 9547776);           //   589,824
    float*    stats    = (float*)(ws + 10137600);          //       512

    repack<<<64, 256, 0, stream>>>(w_off, w_def, woffPack, wdefPack);
    transpose_x<<<NPIX * 2 / 256, 256, 0, stream>>>(x, xT);
    fused_deform<<<NBLK, 512, 0, stream>>>(xT, woffPack, wdefPack, b_off,
                                           out, partial);
    bn_stats<<<1, 1024, 0, stream>>>(partial, gamma, beta, stats);
    bn_apply<<<(NPIX * Cout / 4) / 256, 256, 0, stream>>>(out, stats);
}

// Round 10
// 65.993 us; speedup vs baseline: 1.6874x; 1.6874x over previous
//
#include <hip/hip_runtime.h>
#include <hip/hip_bf16.h>
#include <stdint.h>

static constexpr int NBATCH = 8;
static constexpr int Cin  = 64;
static constexpr int Cout = 64;
static constexpr int H = 96, W = 96;
static constexpr int HW   = H * W;          // 9216
static constexpr int NPIX = NBATCH * HW;    // 73728
static constexpr int NBLK = NPIX / 64;      // 1152
static constexpr int BLK_PER_BATCH = HW / 64; // 144
static constexpr float EPS = 1e-5f;

typedef short  bf16x8 __attribute__((ext_vector_type(8)));
typedef float  f32x4  __attribute__((ext_vector_type(4)));

__device__ inline uint16_t f2bf(float f) {
    __hip_bfloat16 h = __float2bfloat16(f);
    return *reinterpret_cast<uint16_t*>(&h);
}
__device__ inline float bf2f(uint16_t u) {
    union { uint32_t i; float f; } z;
    z.i = ((uint32_t)u) << 16;
    return z.f;
}
__device__ inline void gld_lds16(const void* g, void* l) {
    __builtin_amdgcn_global_load_lds(
        (const __attribute__((address_space(1))) void*)g,
        (__attribute__((address_space(3))) void*)l, 16, 0, 0);
}

// ---------------------------------------------------------------------------
// Kernel 0: pack weights into MFMA B-fragment order, bf16; zero the zeropage.
// ---------------------------------------------------------------------------
__global__ void repack(const float* __restrict__ w_off,
                       const float* __restrict__ w_def,
                       uint16_t* __restrict__ woffPack,
                       uint16_t* __restrict__ wdefPack,
                       float* __restrict__ zeropage) {
    int t0 = blockIdx.x * blockDim.x + threadIdx.x;
    int stride = gridDim.x * blockDim.x;
    if (t0 < 64) zeropage[t0] = 0.f;
    for (int i = t0; i < 72 * 32 * 8; i += stride) {
        int e = i & 7;
        int n = (i >> 3) & 31;
        int sg = i >> 8;
        int k = sg * 8 + e;
        int tap = k >> 6, c = k & 63;
        woffPack[i] = (n < 18) ? f2bf(w_off[(n * Cin + c) * 9 + tap]) : (uint16_t)0;
    }
    for (int i = t0; i < 72 * 64 * 8; i += stride) {
        int e = i & 7;
        int n = (i >> 3) & 63;
        int sg = i >> 9;
        int k = sg * 8 + e;
        int tap = k >> 6, c = k & 63;
        wdefPack[i] = f2bf(w_def[(n * Cin + c) * 9 + tap]);
    }
}

// ---------------------------------------------------------------------------
// Kernel 1: transpose x (NCHW f32) -> xT (N,HW,C) bf16. 2 threads/pixel.
// ---------------------------------------------------------------------------
__global__ __launch_bounds__(256) void transpose_x(const float* __restrict__ x,
                                                   uint16_t* __restrict__ xT) {
    int t = blockIdx.x * 256 + threadIdx.x;      // exact grid: NPIX*2 threads
    int pix  = t >> 1;
    int half = t & 1;
    int b = pix / HW, rem = pix % HW;
    const float* xb = x + (size_t)(b * Cin) * HW + rem + (size_t)(half * 32) * HW;
    uint16_t* o = xT + (size_t)pix * 64 + half * 32;
#pragma unroll
    for (int cg = 0; cg < 4; ++cg) {
        bf16x8 v;
#pragma unroll
        for (int e = 0; e < 8; ++e) v[e] = (short)f2bf(xb[(cg * 8 + e) * HW]);
        *reinterpret_cast<bf16x8*>(o + cg * 8) = v;
    }
}

// ---------------------------------------------------------------------------
// Kernel 2: fused deformable block (R8 structure), 512 thr / 64-pixel tile.
// LDS As: [tap:9][pix:64][slot:8][16B], slot = chunk ^ (pix&7)  (involution).
//  P1: plain im2col via global_load_lds (pre-swizzled source, zeropage OOB)
//  P2: offset GEMM, wave=(wj:2, kq:4) -> osum (alias As) -> offs[64][18]
//  P3: bilinear sampling -> As; setup deduped via shuffle; 2-deep manual
//      load pipeline (issue tap t+1 corners before converting tap t)
//  P4: deform GEMM, wave=(nf:4, kh:2) -> red (alias As) -> ybf (bf16) + BN
// ---------------------------------------------------------------------------
#define P3_SETUP(T, W00,W01,W10,W11,I00,I01,I10,I11)                        \
    if ((T) < 8) {                                                          \
        int src_ = lanebase + (T);                                          \
        W00 = __shfl(w00a, src_); W01 = __shfl(w01a, src_);                 \
        W10 = __shfl(w10a, src_); W11 = __shfl(w11a, src_);                 \
        I00 = __shfl(i00a, src_); I01 = __shfl(i01a, src_);                 \
        I10 = __shfl(i10a, src_); I11 = __shfl(i11a, src_);                 \
    } else {                                                                \
        W00 = w00b; W01 = w01b; W10 = w10b; W11 = w11b;                     \
        I00 = i00b; I01 = i01b; I10 = i10b; I11 = i11b;                     \
    }

#define P3_ISSUE(I00,I01,I10,I11,C00,C01,C10,C11)                           \
    C00 = *reinterpret_cast<const bf16x8*>(basep + (I00) * 64);             \
    C01 = *reinterpret_cast<const bf16x8*>(basep + (I01) * 64);             \
    C10 = *reinterpret_cast<const bf16x8*>(basep + (I10) * 64);             \
    C11 = *reinterpret_cast<const bf16x8*>(basep + (I11) * 64);

#define P3_CONV(T, W00,W01,W10,W11,C00,C01,C10,C11)                         \
    {                                                                       \
        bf16x8 outv_;                                                       \
        _Pragma("unroll")                                                   \
        for (int e = 0; e < 8; ++e) {                                       \
            float s_ = (W00) * bf2f((uint16_t)(C00)[e])                     \
                     + (W01) * bf2f((uint16_t)(C01)[e])                     \
                     + (W10) * bf2f((uint16_t)(C10)[e])                     \
                     + (W11) * bf2f((uint16_t)(C11)[e]);                    \
            outv_[e] = (short)f2bf(s_);                                     \
        }                                                                   \
        *reinterpret_cast<bf16x8*>(&As[(((T) * 64 + pr) * 8 + slot) * 8]) = outv_; \
    }

__global__ __launch_bounds__(512, 4) void fused_deform(
        const uint16_t* __restrict__ xT,
        const uint16_t* __restrict__ woffPack,
        const uint16_t* __restrict__ wdefPack,
        const float* __restrict__ b_off,
        const float* __restrict__ zeropage,
        uint16_t* __restrict__ ybf,
        float* __restrict__ partial) {
    __shared__ __attribute__((aligned(16))) char smem[73728];
    __shared__ float offs[64 * 18];       //  4608 B
    __shared__ float s_red[128];          //   512 B
    short* As   = (short*)smem;           // bf16 im2col tile
    float* osum = (float*)smem;           // [4][64][34] alias (pre-P3)
    float* red  = (float*)smem;           // [2][64][66] alias (post-P4)

    int tid  = threadIdx.x;
    int lane = tid & 63;
    int wv   = tid >> 6;                  // 0..7
    int l15  = lane & 15;
    int lg   = lane >> 4;

    // XCD-aware swizzle: batch b -> XCD b
    int wgid  = (blockIdx.x & 7) * BLK_PER_BATCH + (blockIdx.x >> 3);
    int gpix0 = wgid * 64;
    int b     = gpix0 / HW;
    int rem0  = gpix0 % HW;
    const uint16_t* xTb = xT + (size_t)b * HW * 64;

    // pixel-major mapping for gather phases
    int pr   = (wv << 3) + (lane >> 3);   // local pixel 0..63
    int e8   = lane & 7;                  // channel chunk (8 ch = 16B)
    int slot = e8 ^ (pr & 7);             // LDS swizzle (= pre-swizzled src chunk)
    int remP = rem0 + pr;
    int hP   = remP / W, wP = remP % W;

    // ---- Phase 1: plain im2col via global_load_lds ----
    {
        const uint16_t* gsrc = xTb + slot * 8;    // pre-swizzled source chunk
        char* ldsbase = (char*)As + (size_t)wv * 1024;
#pragma unroll
        for (int tap = 0; tap < 9; ++tap) {
            int yy = hP + tap / 3 - 1;
            int xx = wP + tap % 3 - 1;
            bool ok = (yy >= 0) && (yy < H) && (xx >= 0) && (xx < W);
            const void* g = ok ? (const void*)(gsrc + (yy * W + xx) * 64)
                               : (const void*)zeropage;
            gld_lds16(g, ldsbase + tap * 8192);
        }
    }
    __syncthreads();

    // ---- Phase 2: offset GEMM. wave = (wj = wv&1 N-frag, kq = wv>>1 K-qtr) ----
    {
        int wj = wv & 1;
        int kq = wv >> 1;
        int sbeg = (kq < 2) ? kq * 5 : 2 + kq * 4;     // 0,5,10,14
        int send = (kq < 2) ? sbeg + 5 : sbeg + 4;
        f32x4 oacc[4];
#pragma unroll
        for (int m = 0; m < 4; ++m) oacc[m] = (f32x4){0.f, 0.f, 0.f, 0.f};
        __builtin_amdgcn_s_setprio(1);
        for (int s = sbeg; s < send; ++s) {
            int sg = s * 4 + lg;
            bf16x8 bb = *reinterpret_cast<const bf16x8*>(
                woffPack + (sg * 32 + wj * 16 + l15) * 8);
#pragma unroll
            for (int m = 0; m < 4; ++m) {
                bf16x8 a = *reinterpret_cast<const bf16x8*>(
                    &As[(((sg >> 3) * 64 + m * 16 + l15) * 8 + ((sg & 7) ^ (l15 & 7))) * 8]);
                oacc[m] = __builtin_amdgcn_mfma_f32_16x16x32_bf16(a, bb, oacc[m], 0, 0, 0);
            }
        }
        __builtin_amdgcn_s_setprio(0);
        __syncthreads();     // all As reads done -> safe to alias osum over As
#pragma unroll
        for (int m = 0; m < 4; ++m)
#pragma unroll
            for (int r = 0; r < 4; ++r)
                osum[(kq * 64 + m * 16 + lg * 4 + r) * 34 + wj * 16 + l15] = oacc[m][r];
        __syncthreads();
        for (int i = tid; i < 64 * 18; i += 512) {
            int rr = i / 18, o = i - rr * 18;
            offs[i] = osum[rr * 34 + o] + osum[(64 + rr) * 34 + o]
                    + osum[(128 + rr) * 34 + o] + osum[(192 + rr) * 34 + o] + b_off[o];
        }
        if (tid < 128) s_red[tid] = 0.f;
        __syncthreads();
    }

    // ---- Phase 3: bilinear sampling -> As (dedup setup + 2-deep pipeline) ----
    {
        float hm1 = (float)(hP - 1), wm1 = (float)(wP - 1);
        // setup A: tap = e8 (lane e8 of each 8-lane pixel group)
        float w00a, w01a, w10a, w11a; int i00a, i01a, i10a, i11a;
        {
            int t = e8;
            int ty = (t * 11) >> 5;          // t/3 for t in [0,8]
            int tx = t - 3 * ty;
            float dy = offs[pr * 18 + 2 * t];
            float dx = offs[pr * 18 + 2 * t + 1];
            float py = dy + (float)ty + hm1;
            float px = dx + (float)tx + wm1;
            float y0f = floorf(py), x0f = floorf(px);
            float wy1 = py - y0f, wx1 = px - x0f;
            float wy0 = 1.f - wy1, wx0 = 1.f - wx1;
            int iy0 = (int)y0f, ix0 = (int)x0f;
            int iy1 = iy0 + 1,  ix1 = ix0 + 1;
            bool vy0 = (iy0 >= 0) && (iy0 < H), vy1 = (iy1 >= 0) && (iy1 < H);
            bool vx0 = (ix0 >= 0) && (ix0 < W), vx1 = (ix1 >= 0) && (ix1 < W);
            w00a = (vy0 && vx0) ? wy0 * wx0 : 0.f;
            w01a = (vy0 && vx1) ? wy0 * wx1 : 0.f;
            w10a = (vy1 && vx0) ? wy1 * wx0 : 0.f;
            w11a = (vy1 && vx1) ? wy1 * wx1 : 0.f;
            int cy0 = min(max(iy0, 0), H - 1), cy1 = min(max(iy1, 0), H - 1);
            int cx0 = min(max(ix0, 0), W - 1), cx1 = min(max(ix1, 0), W - 1);
            i00a = cy0 * W + cx0; i01a = cy0 * W + cx1;
            i10a = cy1 * W + cx0; i11a = cy1 * W + cx1;
        }
        // setup B: tap = 8 (every lane, own pixel)
        float w00b, w01b, w10b, w11b; int i00b, i01b, i10b, i11b;
        {
            float dy = offs[pr * 18 + 16];
            float dx = offs[pr * 18 + 17];
            float py = dy + 2.f + hm1;
            float px = dx + 2.f + wm1;
            float y0f = floorf(py), x0f = floorf(px);
            float wy1 = py - y0f, wx1 = px - x0f;
            float wy0 = 1.f - wy1, wx0 = 1.f - wx1;
            int iy0 = (int)y0f, ix0 = (int)x0f;
            int iy1 = iy0 + 1,  ix1 = ix0 + 1;
            bool vy0 = (iy0 >= 0) && (iy0 < H), vy1 = (iy1 >= 0) && (iy1 < H);
            bool vx0 = (ix0 >= 0) && (ix0 < W), vx1 = (ix1 >= 0) && (ix1 < W);
            w00b = (vy0 && vx0) ? wy0 * wx0 : 0.f;
            w01b = (vy0 && vx1) ? wy0 * wx1 : 0.f;
            w10b = (vy1 && vx0) ? wy1 * wx0 : 0.f;
            w11b = (vy1 && vx1) ? wy1 * wx1 : 0.f;
            int cy0 = min(max(iy0, 0), H - 1), cy1 = min(max(iy1, 0), H - 1);
            int cx0 = min(max(ix0, 0), W - 1), cx1 = min(max(ix1, 0), W - 1);
            i00b = cy0 * W + cx0; i01b = cy0 * W + cx1;
            i10b = cy1 * W + cx0; i11b = cy1 * W + cx1;
        }

        const uint16_t* basep = xTb + e8 * 8;
        int lanebase = lane & 56;

        float uA0,uA1,uA2,uA3; int jA0,jA1,jA2,jA3; bf16x8 cA0,cA1,cA2,cA3;
        float uB0,uB1,uB2,uB3; int jB0,jB1,jB2,jB3; bf16x8 cB0,cB1,cB2,cB3;

        P3_SETUP(0, uA0,uA1,uA2,uA3, jA0,jA1,jA2,jA3)
        P3_ISSUE(jA0,jA1,jA2,jA3, cA0,cA1,cA2,cA3)
        P3_SETUP(1, uB0,uB1,uB2,uB3, jB0,jB1,jB2,jB3)
        P3_ISSUE(jB0,jB1,jB2,jB3, cB0,cB1,cB2,cB3)
        P3_CONV(0, uA0,uA1,uA2,uA3, cA0,cA1,cA2,cA3)
        P3_SETUP(2, uA0,uA1,uA2,uA3, jA0,jA1,jA2,jA3)
        P3_ISSUE(jA0,jA1,jA2,jA3, cA0,cA1,cA2,cA3)
        P3_CONV(1, uB0,uB1,uB2,uB3, cB0,cB1,cB2,cB3)
        P3_SETUP(3, uB0,uB1,uB2,uB3, jB0,jB1,jB2,jB3)
        P3_ISSUE(jB0,jB1,jB2,jB3, cB0,cB1,cB2,cB3)
        P3_CONV(2, uA0,uA1,uA2,uA3, cA0,cA1,cA2,cA3)
        P3_SETUP(4, uA0,uA1,uA2,uA3, jA0,jA1,jA2,jA3)
        P3_ISSUE(jA0,jA1,jA2,jA3, cA0,cA1,cA2,cA3)
        P3_CONV(3, uB0,uB1,uB2,uB3, cB0,cB1,cB2,cB3)
        P3_SETUP(5, uB0,uB1,uB2,uB3, jB0,jB1,jB2,jB3)
        P3_ISSUE(jB0,jB1,jB2,jB3, cB0,cB1,cB2,cB3)
        P3_CONV(4, uA0,uA1,uA2,uA3, cA0,cA1,cA2,cA3)
        P3_SETUP(6, uA0,uA1,uA2,uA3, jA0,jA1,jA2,jA3)
        P3_ISSUE(jA0,jA1,jA2,jA3, cA0,cA1,cA2,cA3)
        P3_CONV(5, uB0,uB1,uB2,uB3, cB0,cB1,cB2,cB3)
        P3_SETUP(7, uB0,uB1,uB2,uB3, jB0,jB1,jB2,jB3)
        P3_ISSUE(jB0,jB1,jB2,jB3, cB0,cB1,cB2,cB3)
        P3_CONV(6, uA0,uA1,uA2,uA3, cA0,cA1,cA2,cA3)
        P3_SETUP(8, uA0,uA1,uA2,uA3, jA0,jA1,jA2,jA3)
        P3_ISSUE(jA0,jA1,jA2,jA3, cA0,cA1,cA2,cA3)
        P3_CONV(7, uB0,uB1,uB2,uB3, cB0,cB1,cB2,cB3)
        P3_CONV(8, uA0,uA1,uA2,uA3, cA0,cA1,cA2,cA3)
    }
    __syncthreads();

    // ---- Phase 4: deform GEMM. wave = (nf = wv&3 N-frag, kh = wv>>2 K-half) ----
    {
        int nf = wv & 3;
        int kh = wv >> 2;
        f32x4 acc[4];
#pragma unroll
        for (int m = 0; m < 4; ++m) acc[m] = (f32x4){0.f, 0.f, 0.f, 0.f};
        __builtin_amdgcn_s_setprio(1);
#pragma unroll
        for (int s = 0; s < 9; ++s) {
            int sg = (kh * 9 + s) * 4 + lg;
            bf16x8 bb = *reinterpret_cast<const bf16x8*>(
                wdefPack + (sg * 64 + nf * 16 + l15) * 8);
#pragma unroll
            for (int m = 0; m < 4; ++m) {
                bf16x8 a = *reinterpret_cast<const bf16x8*>(
                    &As[(((sg >> 3) * 64 + m * 16 + l15) * 8 + ((sg & 7) ^ (l15 & 7))) * 8]);
                acc[m] = __builtin_amdgcn_mfma_f32_16x16x32_bf16(a, bb, acc[m], 0, 0, 0);
            }
        }
        __builtin_amdgcn_s_setprio(0);
        __syncthreads();     // all As reads done -> safe to alias red over As
#pragma unroll
        for (int m = 0; m < 4; ++m)
#pragma unroll
            for (int r = 0; r < 4; ++r)
                red[(kh * 64 + m * 16 + lg * 4 + r) * 66 + nf * 16 + l15] = acc[m][r];
        __syncthreads();

        // final: thread (c = lane, rg = wv) -> rows rg*8..rg*8+7, cout c
        int c  = lane;
        int rg = wv;
        bf16x8 ov;
        float s = 0.f, q = 0.f;
#pragma unroll
        for (int k2 = 0; k2 < 8; ++k2) {
            int r = rg * 8 + k2;
            float v = red[r * 66 + c] + red[(64 + r) * 66 + c];
            ov[k2] = (short)f2bf(v);
            s += v; q += v * v;
        }
        *reinterpret_cast<bf16x8*>(
            ybf + ((size_t)b * Cout + c) * HW + rem0 + rg * 8) = ov;
        atomicAdd(&s_red[c], s);
        atomicAdd(&s_red[64 + c], q);
    }
    __syncthreads();
    if (tid < 128) partial[(size_t)wgid * 128 + tid] = s_red[tid];
}

// ---------------------------------------------------------------------------
// Kernel 3a: stage-1 BN reduce: 72 blocks x 16 tiles -> partial2[72][128]
// ---------------------------------------------------------------------------
__global__ __launch_bounds__(256) void bn_reduce1(const float* __restrict__ partial,
                                                  float* __restrict__ partial2) {
    __shared__ float red[256];
    int ch = threadIdx.x & 127;
    int g  = threadIdx.x >> 7;
    float s = 0.f;
#pragma unroll
    for (int r = 0; r < 8; ++r)
        s += partial[(size_t)(blockIdx.x * 16 + g * 8 + r) * 128 + ch];
    red[threadIdx.x] = s;
    __syncthreads();
    if (g == 0)
        partial2[(size_t)blockIdx.x * 128 + ch] = red[ch] + red[128 + ch];
}

// ---------------------------------------------------------------------------
// Kernel 3b: stage-2 -> per-channel scale/shift
// ---------------------------------------------------------------------------
__global__ void bn_stats2(const float* __restrict__ partial2,
                          const float* __restrict__ gamma,
                          const float* __restrict__ beta,
                          float* __restrict__ stats) {
    __shared__ float red[256];
    int ch = threadIdx.x & 127;
    int g  = threadIdx.x >> 7;
    float s = 0.f;
    for (int i = 0; i < 36; ++i)
        s += partial2[(size_t)(g * 36 + i) * 128 + ch];
    red[threadIdx.x] = s;
    __syncthreads();
    if (threadIdx.x < 64) {
        int c = threadIdx.x;
        float sum = red[c] + red[128 + c];
        float sq  = red[64 + c] + red[192 + c];
        float mean = sum / (float)NPIX;
        float var  = sq / (float)NPIX - mean * mean;
        float v    = var + EPS;
        float inv  = rsqrtf(v);
        inv = inv * (1.5f - 0.5f * v * inv * inv);
        float sc = gamma[c] * inv;
        stats[c]      = sc;
        stats[64 + c] = beta[c] - mean * sc;
    }
}

// ---------------------------------------------------------------------------
// Kernel 4: scale/shift/ReLU: read bf16 y, write f32 out. 8 elems/thread.
// ---------------------------------------------------------------------------
__global__ __launch_bounds__(256) void bn_apply(const uint16_t* __restrict__ ybf,
                                                float* __restrict__ out,
                                                const float* __restrict__ stats) {
    int t = blockIdx.x * blockDim.x + threadIdx.x;   // exact: NPIX*64/8 threads
    int e = t * 8;
    int ch = (e / HW) & 63;
    float sc = stats[ch];
    float sh = stats[64 + ch];
    bf16x8 v = *reinterpret_cast<const bf16x8*>(ybf + e);
    f32x4 o0, o1;
#pragma unroll
    for (int i = 0; i < 4; ++i) {
        o0[i] = fmaxf(bf2f((uint16_t)v[i])     * sc + sh, 0.f);
        o1[i] = fmaxf(bf2f((uint16_t)v[4 + i]) * sc + sh, 0.f);
    }
    *reinterpret_cast<f32x4*>(out + e)     = o0;
    *reinterpret_cast<f32x4*>(out + e + 4) = o1;
}

// ---------------------------------------------------------------------------
extern "C" void kernel_launch(void* const* d_in, const int* in_sizes, int n_in,
                              void* d_out, int out_size, void* d_ws, size_t ws_size,
                              hipStream_t stream) {
    const float* x     = (const float*)d_in[0];
    const float* w_off = (const float*)d_in[1];
    const float* b_off = (const float*)d_in[2];
    const float* w_def = (const float*)d_in[3];
    // d_in[4] = b_def: constant shift, cancels exactly in BatchNorm — omitted
    const float* gamma = (const float*)d_in[5];
    const float* beta  = (const float*)d_in[6];
    float* out = (float*)d_out;
    char*  ws  = (char*)d_ws;

    // ws layout (bytes)
    uint16_t* xT       = (uint16_t*)ws;                    // 9,437,184
    uint16_t* woffPack = (uint16_t*)(ws + 9437184);        //    36,864
    uint16_t* wdefPack = (uint16_t*)(ws + 9474048);        //    73,728
    float*    partial  = (float*)(ws + 9547776);           //   589,824
    float*    partial2 = (float*)(ws + 10137600);          //    36,864
    float*    stats    = (float*)(ws + 10174464);          //       512
    float*    zeropage = (float*)(ws + 10174976);          //       256
    uint16_t* ybf      = (uint16_t*)(ws + 10175232);       // 9,437,184

    repack<<<64, 256, 0, stream>>>(w_off, w_def, woffPack, wdefPack, zeropage);
    transpose_x<<<NPIX * 2 / 256, 256, 0, stream>>>(x, xT);
    fused_deform<<<NBLK, 512, 0, stream>>>(xT, woffPack, wdefPack, b_off,
                                           zeropage, ybf, partial);
    bn_reduce1<<<72, 256, 0, stream>>>(partial, partial2);
    bn_stats2<<<1, 256, 0, stream>>>(partial2, gamma, beta, stats);
    bn_apply<<<(NPIX * Cout / 8) / 256, 256, 0, stream>>>(ybf, out, stats);
}

// Round 11
// 61.436 us; speedup vs baseline: 1.8125x; 1.0742x over previous
//
#include <hip/hip_runtime.h>
#include <hip/hip_bf16.h>
#include <stdint.h>

static constexpr int NBATCH = 8;
static constexpr int Cin  = 64;
static constexpr int Cout = 64;
static constexpr int H = 96, W = 96;
static constexpr int HW   = H * W;          // 9216
static constexpr int NPIX = NBATCH * HW;    // 73728
static constexpr int NBLK = NPIX / 64;      // 1152
static constexpr int BLK_PER_BATCH = HW / 64; // 144
static constexpr float EPS = 1e-5f;

typedef short    bf16x8 __attribute__((ext_vector_type(8)));
typedef float    f32x4  __attribute__((ext_vector_type(4)));
typedef uint32_t u32x4  __attribute__((ext_vector_type(4)));

__device__ inline uint16_t f2bf(float f) {
    __hip_bfloat16 h = __float2bfloat16(f);
    return *reinterpret_cast<uint16_t*>(&h);
}
__device__ inline float bf2f(uint16_t u) {
    union { uint32_t i; float f; } z;
    z.i = ((uint32_t)u) << 16;
    return z.f;
}
__device__ inline float lo_bf(uint32_t w) {
    union { uint32_t i; float f; } z; z.i = w << 16; return z.f;
}
__device__ inline float hi_bf(uint32_t w) {
    union { uint32_t i; float f; } z; z.i = w & 0xffff0000u; return z.f;
}
__device__ inline uint32_t pack_trunc(float lo, float hi) {
    union { float f; uint32_t i; } a, b;
    a.f = lo; b.f = hi;
    return (b.i & 0xffff0000u) | (a.i >> 16);
}
__device__ inline void gld_lds16(const void* g, void* l) {
    __builtin_amdgcn_global_load_lds(
        (const __attribute__((address_space(1))) void*)g,
        (__attribute__((address_space(3))) void*)l, 16, 0, 0);
}

// ---------------------------------------------------------------------------
// Kernel 1: transpose x (NCHW f32) -> xT (N,HW,C) bf16 (2 threads/pixel)
//           + weight repack (blocks 0..63) + zeropage (block 0).
// ---------------------------------------------------------------------------
__global__ __launch_bounds__(256) void transpose_pack(
        const float* __restrict__ x,
        const float* __restrict__ w_off,
        const float* __restrict__ w_def,
        uint16_t* __restrict__ xT,
        uint16_t* __restrict__ woffPack,
        uint16_t* __restrict__ wdefPack,
        float* __restrict__ zeropage) {
    int t = blockIdx.x * 256 + threadIdx.x;      // exact grid: NPIX*2 threads
    int pix  = t >> 1;
    int half = t & 1;
    int b = pix / HW, rem = pix % HW;
    const float* xb = x + (size_t)(b * Cin) * HW + rem + (size_t)(half * 32) * HW;
    uint16_t* o = xT + (size_t)pix * 64 + half * 32;
#pragma unroll
    for (int cg = 0; cg < 4; ++cg) {
        bf16x8 v;
#pragma unroll
        for (int e = 0; e < 8; ++e) v[e] = (short)f2bf(xb[(cg * 8 + e) * HW]);
        *reinterpret_cast<bf16x8*>(o + cg * 8) = v;
    }
    // weight packing on the first 64 blocks (grid-stride 16384)
    if (blockIdx.x < 64) {
        int t0 = blockIdx.x * 256 + threadIdx.x;
        if (t0 < 64) zeropage[t0] = 0.f;
        for (int i = t0; i < 72 * 32 * 8; i += 64 * 256) {
            int e = i & 7;
            int n = (i >> 3) & 31;
            int sg = i >> 8;
            int k = sg * 8 + e;
            int tap = k >> 6, c = k & 63;
            woffPack[i] = (n < 18) ? f2bf(w_off[(n * Cin + c) * 9 + tap]) : (uint16_t)0;
        }
        for (int i = t0; i < 72 * 64 * 8; i += 64 * 256) {
            int e = i & 7;
            int n = (i >> 3) & 63;
            int sg = i >> 9;
            int k = sg * 8 + e;
            int tap = k >> 6, c = k & 63;
            wdefPack[i] = f2bf(w_def[(n * Cin + c) * 9 + tap]);
        }
    }
}

// ---------------------------------------------------------------------------
// Kernel 2: fused deformable block (R8/R10 structure), 512 thr / 64-px tile.
// LDS As: [tap:9][pix:64][slot:8][16B], slot = chunk ^ (pix&7)  (involution).
//  P1: plain im2col via global_load_lds (pre-swizzled source, zeropage OOB)
//  P2: offset GEMM, wave=(wj:2, kq:4) -> osum (alias As) -> offs[64][18]
//  P3: bilinear sampling -> As; setup deduped via shuffle; u32 corner loads,
//      1-instr bf16 unpacks, truncation pair-pack (no per-elem RNE convert)
//  P4: deform GEMM, wave=(nf:4, kh:2) -> red (alias As) -> ybf (bf16) + BN
// ---------------------------------------------------------------------------
#define P3_SETUP(T, W00,W01,W10,W11,I00,I01,I10,I11)                        \
    if ((T) < 8) {                                                          \
        int src_ = lanebase + (T);                                          \
        W00 = __shfl(w00a, src_); W01 = __shfl(w01a, src_);                 \
        W10 = __shfl(w10a, src_); W11 = __shfl(w11a, src_);                 \
        I00 = __shfl(i00a, src_); I01 = __shfl(i01a, src_);                 \
        I10 = __shfl(i10a, src_); I11 = __shfl(i11a, src_);                 \
    } else {                                                                \
        W00 = w00b; W01 = w01b; W10 = w10b; W11 = w11b;                     \
        I00 = i00b; I01 = i01b; I10 = i10b; I11 = i11b;                     \
    }

#define P3_ISSUE(I00,I01,I10,I11,C00,C01,C10,C11)                           \
    C00 = *reinterpret_cast<const u32x4*>(basep + (I00) * 64);              \
    C01 = *reinterpret_cast<const u32x4*>(basep + (I01) * 64);              \
    C10 = *reinterpret_cast<const u32x4*>(basep + (I10) * 64);              \
    C11 = *reinterpret_cast<const u32x4*>(basep + (I11) * 64);

#define P3_CONV(T, W00,W01,W10,W11,C00,C01,C10,C11)                         \
    {                                                                       \
        u32x4 outv_;                                                        \
        _Pragma("unroll")                                                   \
        for (int i = 0; i < 4; ++i) {                                       \
            float slo_ = (W00) * lo_bf((C00)[i]) + (W01) * lo_bf((C01)[i])  \
                       + (W10) * lo_bf((C10)[i]) + (W11) * lo_bf((C11)[i]); \
            float shi_ = (W00) * hi_bf((C00)[i]) + (W01) * hi_bf((C01)[i])  \
                       + (W10) * hi_bf((C10)[i]) + (W11) * hi_bf((C11)[i]); \
            outv_[i] = pack_trunc(slo_, shi_);                              \
        }                                                                   \
        *reinterpret_cast<u32x4*>(&As[(((T) * 64 + pr) * 8 + slot) * 8]) = outv_; \
    }

__global__ __launch_bounds__(512, 4) void fused_deform(
        const uint16_t* __restrict__ xT,
        const uint16_t* __restrict__ woffPack,
        const uint16_t* __restrict__ wdefPack,
        const float* __restrict__ b_off,
        const float* __restrict__ zeropage,
        uint16_t* __restrict__ ybf,
        float* __restrict__ partial) {
    __shared__ __attribute__((aligned(16))) char smem[73728];
    __shared__ float offs[64 * 18];       //  4608 B
    __shared__ float s_red[128];          //   512 B
    short* As   = (short*)smem;           // bf16 im2col tile
    float* osum = (float*)smem;           // [4][64][34] alias (pre-P3)
    float* red  = (float*)smem;           // [2][64][66] alias (post-P4)

    int tid  = threadIdx.x;
    int lane = tid & 63;
    int wv   = tid >> 6;                  // 0..7
    int l15  = lane & 15;
    int lg   = lane >> 4;

    // XCD-aware swizzle: batch b -> XCD b
    int wgid  = (blockIdx.x & 7) * BLK_PER_BATCH + (blockIdx.x >> 3);
    int gpix0 = wgid * 64;
    int b     = gpix0 / HW;
    int rem0  = gpix0 % HW;
    const uint16_t* xTb = xT + (size_t)b * HW * 64;

    // pixel-major mapping for gather phases
    int pr   = (wv << 3) + (lane >> 3);   // local pixel 0..63
    int e8   = lane & 7;                  // channel chunk (8 ch = 16B)
    int slot = e8 ^ (pr & 7);             // LDS swizzle (= pre-swizzled src chunk)
    int remP = rem0 + pr;
    int hP   = remP / W, wP = remP % W;

    // ---- Phase 1: plain im2col via global_load_lds ----
    {
        const uint16_t* gsrc = xTb + slot * 8;    // pre-swizzled source chunk
        char* ldsbase = (char*)As + (size_t)wv * 1024;
#pragma unroll
        for (int tap = 0; tap < 9; ++tap) {
            int yy = hP + tap / 3 - 1;
            int xx = wP + tap % 3 - 1;
            bool ok = (yy >= 0) && (yy < H) && (xx >= 0) && (xx < W);
            const void* g = ok ? (const void*)(gsrc + (yy * W + xx) * 64)
                               : (const void*)zeropage;
            gld_lds16(g, ldsbase + tap * 8192);
        }
    }
    __syncthreads();

    // ---- Phase 2: offset GEMM. wave = (wj = wv&1 N-frag, kq = wv>>1 K-qtr) ----
    {
        int wj = wv & 1;
        int kq = wv >> 1;
        int sbeg = (kq < 2) ? kq * 5 : 2 + kq * 4;     // 0,5,10,14
        int send = (kq < 2) ? sbeg + 5 : sbeg + 4;
        f32x4 oacc[4];
#pragma unroll
        for (int m = 0; m < 4; ++m) oacc[m] = (f32x4){0.f, 0.f, 0.f, 0.f};
        __builtin_amdgcn_s_setprio(1);
        for (int s = sbeg; s < send; ++s) {
            int sg = s * 4 + lg;
            bf16x8 bb = *reinterpret_cast<const bf16x8*>(
                woffPack + (sg * 32 + wj * 16 + l15) * 8);
#pragma unroll
            for (int m = 0; m < 4; ++m) {
                bf16x8 a = *reinterpret_cast<const bf16x8*>(
                    &As[(((sg >> 3) * 64 + m * 16 + l15) * 8 + ((sg & 7) ^ (l15 & 7))) * 8]);
                oacc[m] = __builtin_amdgcn_mfma_f32_16x16x32_bf16(a, bb, oacc[m], 0, 0, 0);
            }
        }
        __builtin_amdgcn_s_setprio(0);
        __syncthreads();     // all As reads done -> safe to alias osum over As
#pragma unroll
        for (int m = 0; m < 4; ++m)
#pragma unroll
            for (int r = 0; r < 4; ++r)
                osum[(kq * 64 + m * 16 + lg * 4 + r) * 34 + wj * 16 + l15] = oacc[m][r];
        __syncthreads();
        for (int i = tid; i < 64 * 18; i += 512) {
            int rr = i / 18, o = i - rr * 18;
            offs[i] = osum[rr * 34 + o] + osum[(64 + rr) * 34 + o]
                    + osum[(128 + rr) * 34 + o] + osum[(192 + rr) * 34 + o] + b_off[o];
        }
        if (tid < 128) s_red[tid] = 0.f;
        __syncthreads();
    }

    // ---- Phase 3: bilinear sampling -> As (dedup setup + 2-deep pipeline) ----
    {
        float hm1 = (float)(hP - 1), wm1 = (float)(wP - 1);
        // setup A: tap = e8 (lane e8 of each 8-lane pixel group)
        float w00a, w01a, w10a, w11a; int i00a, i01a, i10a, i11a;
        {
            int t = e8;
            int ty = (t * 11) >> 5;          // t/3 for t in [0,8]
            int tx = t - 3 * ty;
            float dy = offs[pr * 18 + 2 * t];
            float dx = offs[pr * 18 + 2 * t + 1];
            float py = dy + (float)ty + hm1;
            float px = dx + (float)tx + wm1;
            float y0f = floorf(py), x0f = floorf(px);
            float wy1 = py - y0f, wx1 = px - x0f;
            float wy0 = 1.f - wy1, wx0 = 1.f - wx1;
            int iy0 = (int)y0f, ix0 = (int)x0f;
            int iy1 = iy0 + 1,  ix1 = ix0 + 1;
            bool vy0 = (iy0 >= 0) && (iy0 < H), vy1 = (iy1 >= 0) && (iy1 < H);
            bool vx0 = (ix0 >= 0) && (ix0 < W), vx1 = (ix1 >= 0) && (ix1 < W);
            w00a = (vy0 && vx0) ? wy0 * wx0 : 0.f;
            w01a = (vy0 && vx1) ? wy0 * wx1 : 0.f;
            w10a = (vy1 && vx0) ? wy1 * wx0 : 0.f;
            w11a = (vy1 && vx1) ? wy1 * wx1 : 0.f;
            int cy0 = min(max(iy0, 0), H - 1), cy1 = min(max(iy1, 0), H - 1);
            int cx0 = min(max(ix0, 0), W - 1), cx1 = min(max(ix1, 0), W - 1);
            i00a = cy0 * W + cx0; i01a = cy0 * W + cx1;
            i10a = cy1 * W + cx0; i11a = cy1 * W + cx1;
        }
        // setup B: tap = 8 (every lane, own pixel)
        float w00b, w01b, w10b, w11b; int i00b, i01b, i10b, i11b;
        {
            float dy = offs[pr * 18 + 16];
            float dx = offs[pr * 18 + 17];
            float py = dy + 2.f + hm1;
            float px = dx + 2.f + wm1;
            float y0f = floorf(py), x0f = floorf(px);
            float wy1 = py - y0f, wx1 = px - x0f;
            float wy0 = 1.f - wy1, wx0 = 1.f - wx1;
            int iy0 = (int)y0f, ix0 = (int)x0f;
            int iy1 = iy0 + 1,  ix1 = ix0 + 1;
            bool vy0 = (iy0 >= 0) && (iy0 < H), vy1 = (iy1 >= 0) && (iy1 < H);
            bool vx0 = (ix0 >= 0) && (ix0 < W), vx1 = (ix1 >= 0) && (ix1 < W);
            w00b = (vy0 && vx0) ? wy0 * wx0 : 0.f;
            w01b = (vy0 && vx1) ? wy0 * wx1 : 0.f;
            w10b = (vy1 && vx0) ? wy1 * wx0 : 0.f;
            w11b = (vy1 && vx1) ? wy1 * wx1 : 0.f;
            int cy0 = min(max(iy0, 0), H - 1), cy1 = min(max(iy1, 0), H - 1);
            int cx0 = min(max(ix0, 0), W - 1), cx1 = min(max(ix1, 0), W - 1);
            i00b = cy0 * W + cx0; i01b = cy0 * W + cx1;
            i10b = cy1 * W + cx0; i11b = cy1 * W + cx1;
        }

        const uint16_t* basep = xTb + e8 * 8;
        int lanebase = lane & 56;

        float uA0,uA1,uA2,uA3; int jA0,jA1,jA2,jA3; u32x4 cA0,cA1,cA2,cA3;
        float uB0,uB1,uB2,uB3; int jB0,jB1,jB2,jB3; u32x4 cB0,cB1,cB2,cB3;

        P3_SETUP(0, uA0,uA1,uA2,uA3, jA0,jA1,jA2,jA3)
        P3_ISSUE(jA0,jA1,jA2,jA3, cA0,cA1,cA2,cA3)
        P3_SETUP(1, uB0,uB1,uB2,uB3, jB0,jB1,jB2,jB3)
        P3_ISSUE(jB0,jB1,jB2,jB3, cB0,cB1,cB2,cB3)
        P3_CONV(0, uA0,uA1,uA2,uA3, cA0,cA1,cA2,cA3)
        P3_SETUP(2, uA0,uA1,uA2,uA3, jA0,jA1,jA2,jA3)
        P3_ISSUE(jA0,jA1,jA2,jA3, cA0,cA1,cA2,cA3)
        P3_CONV(1, uB0,uB1,uB2,uB3, cB0,cB1,cB2,cB3)
        P3_SETUP(3, uB0,uB1,uB2,uB3, jB0,jB1,jB2,jB3)
        P3_ISSUE(jB0,jB1,jB2,jB3, cB0,cB1,cB2,cB3)
        P3_CONV(2, uA0,uA1,uA2,uA3, cA0,cA1,cA2,cA3)
        P3_SETUP(4, uA0,uA1,uA2,uA3, jA0,jA1,jA2,jA3)
        P3_ISSUE(jA0,jA1,jA2,jA3, cA0,cA1,cA2,cA3)
        P3_CONV(3, uB0,uB1,uB2,uB3, cB0,cB1,cB2,cB3)
        P3_SETUP(5, uB0,uB1,uB2,uB3, jB0,jB1,jB2,jB3)
        P3_ISSUE(jB0,jB1,jB2,jB3, cB0,cB1,cB2,cB3)
        P3_CONV(4, uA0,uA1,uA2,uA3, cA0,cA1,cA2,cA3)
        P3_SETUP(6, uA0,uA1,uA2,uA3, jA0,jA1,jA2,jA3)
        P3_ISSUE(jA0,jA1,jA2,jA3, cA0,cA1,cA2,cA3)
        P3_CONV(5, uB0,uB1,uB2,uB3, cB0,cB1,cB2,cB3)
        P3_SETUP(7, uB0,uB1,uB2,uB3, jB0,jB1,jB2,jB3)
        P3_ISSUE(jB0,jB1,jB2,jB3, cB0,cB1,cB2,cB3)
        P3_CONV(6, uA0,uA1,uA2,uA3, cA0,cA1,cA2,cA3)
        P3_SETUP(8, uA0,uA1,uA2,uA3, jA0,jA1,jA2,jA3)
        P3_ISSUE(jA0,jA1,jA2,jA3, cA0,cA1,cA2,cA3)
        P3_CONV(7, uB0,uB1,uB2,uB3, cB0,cB1,cB2,cB3)
        P3_CONV(8, uA0,uA1,uA2,uA3, cA0,cA1,cA2,cA3)
    }
    __syncthreads();

    // ---- Phase 4: deform GEMM. wave = (nf = wv&3 N-frag, kh = wv>>2 K-half) ----
    {
        int nf = wv & 3;
        int kh = wv >> 2;
        f32x4 acc[4];
#pragma unroll
        for (int m = 0; m < 4; ++m) acc[m] = (f32x4){0.f, 0.f, 0.f, 0.f};
        __builtin_amdgcn_s_setprio(1);
#pragma unroll
        for (int s = 0; s < 9; ++s) {
            int sg = (kh * 9 + s) * 4 + lg;
            bf16x8 bb = *reinterpret_cast<const bf16x8*>(
                wdefPack + (sg * 64 + nf * 16 + l15) * 8);
#pragma unroll
            for (int m = 0; m < 4; ++m) {
                bf16x8 a = *reinterpret_cast<const bf16x8*>(
                    &As[(((sg >> 3) * 64 + m * 16 + l15) * 8 + ((sg & 7) ^ (l15 & 7))) * 8]);
                acc[m] = __builtin_amdgcn_mfma_f32_16x16x32_bf16(a, bb, acc[m], 0, 0, 0);
            }
        }
        __builtin_amdgcn_s_setprio(0);
        __syncthreads();     // all As reads done -> safe to alias red over As
#pragma unroll
        for (int m = 0; m < 4; ++m)
#pragma unroll
            for (int r = 0; r < 4; ++r)
                red[(kh * 64 + m * 16 + lg * 4 + r) * 66 + nf * 16 + l15] = acc[m][r];
        __syncthreads();

        // final: thread (c = lane, rg = wv) -> rows rg*8..rg*8+7, cout c
        int c  = lane;
        int rg = wv;
        bf16x8 ov;
        float s = 0.f, q = 0.f;
#pragma unroll
        for (int k2 = 0; k2 < 8; ++k2) {
            int r = rg * 8 + k2;
            float v = red[r * 66 + c] + red[(64 + r) * 66 + c];
            ov[k2] = (short)f2bf(v);
            s += v; q += v * v;
        }
        *reinterpret_cast<bf16x8*>(
            ybf + ((size_t)b * Cout + c) * HW + rem0 + rg * 8) = ov;
        atomicAdd(&s_red[c], s);
        atomicAdd(&s_red[64 + c], q);
    }
    __syncthreads();
    if (tid < 128) partial[(size_t)wgid * 128 + tid] = s_red[tid];
}

// ---------------------------------------------------------------------------
// Kernel 3a: stage-1 BN reduce: 72 blocks x 16 tiles -> partial2[72][128]
// ---------------------------------------------------------------------------
__global__ __launch_bounds__(256) void bn_reduce1(const float* __restrict__ partial,
                                                  float* __restrict__ partial2) {
    __shared__ float red[256];
    int ch = threadIdx.x & 127;
    int g  = threadIdx.x >> 7;
    float s = 0.f;
#pragma unroll
    for (int r = 0; r < 8; ++r)
        s += partial[(size_t)(blockIdx.x * 16 + g * 8 + r) * 128 + ch];
    red[threadIdx.x] = s;
    __syncthreads();
    if (g == 0)
        partial2[(size_t)blockIdx.x * 128 + ch] = red[ch] + red[128 + ch];
}

// ---------------------------------------------------------------------------
// Kernel 3b: stage-2 -> per-channel scale/shift
// ---------------------------------------------------------------------------
__global__ void bn_stats2(const float* __restrict__ partial2,
                          const float* __restrict__ gamma,
                          const float* __restrict__ beta,
                          float* __restrict__ stats) {
    __shared__ float red[256];
    int ch = threadIdx.x & 127;
    int g  = threadIdx.x >> 7;
    float s = 0.f;
    for (int i = 0; i < 36; ++i)
        s += partial2[(size_t)(g * 36 + i) * 128 + ch];
    red[threadIdx.x] = s;
    __syncthreads();
    if (threadIdx.x < 64) {
        int c = threadIdx.x;
        float sum = red[c] + red[128 + c];
        float sq  = red[64 + c] + red[192 + c];
        float mean = sum / (float)NPIX;
        float var  = sq / (float)NPIX - mean * mean;
        float v    = var + EPS;
        float inv  = rsqrtf(v);
        inv = inv * (1.5f - 0.5f * v * inv * inv);
        float sc = gamma[c] * inv;
        stats[c]      = sc;
        stats[64 + c] = beta[c] - mean * sc;
    }
}

// ---------------------------------------------------------------------------
// Kernel 4: scale/shift/ReLU: read bf16 y, write f32 out. 8 elems/thread.
// ---------------------------------------------------------------------------
__global__ __launch_bounds__(256) void bn_apply(const uint16_t* __restrict__ ybf,
                                                float* __restrict__ out,
                                                const float* __restrict__ stats) {
    int t = blockIdx.x * blockDim.x + threadIdx.x;   // exact: NPIX*64/8 threads
    int e = t * 8;
    int ch = (e / HW) & 63;
    float sc = stats[ch];
    float sh = stats[64 + ch];
    bf16x8 v = *reinterpret_cast<const bf16x8*>(ybf + e);
    f32x4 o0, o1;
#pragma unroll
    for (int i = 0; i < 4; ++i) {
        o0[i] = fmaxf(bf2f((uint16_t)v[i])     * sc + sh, 0.f);
        o1[i] = fmaxf(bf2f((uint16_t)v[4 + i]) * sc + sh, 0.f);
    }
    *reinterpret_cast<f32x4*>(out + e)     = o0;
    *reinterpret_cast<f32x4*>(out + e + 4) = o1;
}

// ---------------------------------------------------------------------------
extern "C" void kernel_launch(void* const* d_in, const int* in_sizes, int n_in,
                              void* d_out, int out_size, void* d_ws, size_t ws_size,
                              hipStream_t stream) {
    const float* x     = (const float*)d_in[0];
    const float* w_off = (const float*)d_in[1];
    const float* b_off = (const float*)d_in[2];
    const float* w_def = (const float*)d_in[3];
    // d_in[4] = b_def: constant shift, cancels exactly in BatchNorm — omitted
    const float* gamma = (const float*)d_in[5];
    const float* beta  = (const float*)d_in[6];
    float* out = (float*)d_out;
    char*  ws  = (char*)d_ws;

    // ws layout (bytes)
    uint16_t* xT       = (uint16_t*)ws;                    // 9,437,184
    uint16_t* woffPack = (uint16_t*)(ws + 9437184);        //    36,864
    uint16_t* wdefPack = (uint16_t*)(ws + 9474048);        //    73,728
    float*    partial  = (float*)(ws + 9547776);           //   589,824
    float*    partial2 = (float*)(ws + 10137600);          //    36,864
    float*    stats    = (float*)(ws + 10174464);          //       512
    float*    zeropage = (float*)(ws + 10174976);          //       256
    uint16_t* ybf      = (uint16_t*)(ws + 10175232);       // 9,437,184

    transpose_pack<<<NPIX * 2 / 256, 256, 0, stream>>>(x, w_off, w_def, xT,
                                                       woffPack, wdefPack, zeropage);
    fused_deform<<<NBLK, 512, 0, stream>>>(xT, woffPack, wdefPack, b_off,
                                           zeropage, ybf, partial);
    bn_reduce1<<<72, 256, 0, stream>>>(partial, partial2);
    bn_stats2<<<1, 256, 0, stream>>>(partial2, gamma, beta, stats);
    bn_apply<<<(NPIX * Cout / 8) / 256, 256, 0, stream>>>(ybf, out, stats);
}